// Round 9
// baseline (166.829 us; speedup 1.0000x reference)
//
#include <hip/hip_runtime.h>
#include <stdint.h>

typedef __attribute__((ext_vector_type(8))) short short8;
typedef __attribute__((ext_vector_type(4))) float f32x4;

__device__ __forceinline__ uint32_t f2bf1(float f) {
  union { float f; uint32_t u; } c; c.f = f;
  return (c.u + 0x7FFFu + ((c.u >> 16) & 1u)) >> 16;
}
__device__ __forceinline__ uint32_t pack2bf(float lo, float hi) {
  return f2bf1(lo) | (f2bf1(hi) << 16);
}
__device__ __forceinline__ float bflo(uint32_t u) {
  union { uint32_t u; float f; } c; c.u = u << 16; return c.f;
}
__device__ __forceinline__ float bfhi(uint32_t u) {
  union { uint32_t u; float f; } c; c.u = u & 0xFFFF0000u; return c.f;
}

// ------- prep: count+pos (deg atomics) + xconv (x->bf16) + wconv (W->bf16) --
// block ranges: [0,cB) count | [cB,cB+xB) xconv | [cB+xB, cB+xB+64) wconv
__global__ void __launch_bounds__(256) prep_kernel(
    const int* __restrict__ dst, uint32_t* __restrict__ deg,
    uint32_t* __restrict__ pos,
    const float* __restrict__ x, uint32_t* __restrict__ cat,
    const float* __restrict__ W, uint32_t* __restrict__ Wb,
    int E, int N, int cB, int xB) {
  int b = blockIdx.x;
  if (b < cB) {
    int e = b * 256 + threadIdx.x;
    if (e < E) pos[e] = atomicAdd(&deg[dst[e]], 1u);
  } else if (b < cB + xB) {
    int n = (b - cB) * 4 + (threadIdx.x >> 6);
    if (n >= N) return;
    int lane = threadIdx.x & 63;
    float2 xv = reinterpret_cast<const float2*>(x + (size_t)n * 128)[lane];
    cat[(size_t)n * 128 + lane] = pack2bf(xv.x, xv.y);
  } else {
    int i = (b - cB - xB) * 256 + threadIdx.x;  // packs 2 floats of W
    if (i < 16384) {
      float2 wv = reinterpret_cast<const float2*>(W)[i];
      Wb[i] = pack2bf(wv.x, wv.y);
    }
  }
}

// ---------------- scan stage 1: per-1024-chunk exclusive partials -----------
__global__ void __launch_bounds__(256) scan1_kernel(
    const uint32_t* __restrict__ deg, uint32_t* __restrict__ partial,
    uint32_t* __restrict__ bsum, int N) {
  __shared__ uint32_t sm[256];
  int t = threadIdx.x;
  int base = blockIdx.x * 1024 + t * 4;
  uint32_t d0 = 0, d1 = 0, d2 = 0, d3 = 0;
  if (base + 3 < N) {
    uint4 v = *reinterpret_cast<const uint4*>(deg + base);
    d0 = v.x; d1 = v.y; d2 = v.z; d3 = v.w;
  } else {
    if (base + 0 < N) d0 = deg[base + 0];
    if (base + 1 < N) d1 = deg[base + 1];
    if (base + 2 < N) d2 = deg[base + 2];
    if (base + 3 < N) d3 = deg[base + 3];
  }
  uint32_t s4 = d0 + d1 + d2 + d3;
  sm[t] = s4;
  uint32_t v = s4;
  __syncthreads();
  #pragma unroll
  for (int off = 1; off < 256; off <<= 1) {
    uint32_t u = (t >= off) ? sm[t - off] : 0u;
    __syncthreads();
    v += u;
    sm[t] = v;
    __syncthreads();
  }
  uint32_t ex = v - s4;
  if (base + 0 < N) partial[base + 0] = ex;
  if (base + 1 < N) partial[base + 1] = ex + d0;
  if (base + 2 < N) partial[base + 2] = ex + d0 + d1;
  if (base + 3 < N) partial[base + 3] = ex + d0 + d1 + d2;
  if (t == 255) bsum[blockIdx.x] = v;
}

// ---------------- scan stage 2: exclusive scan of block sums ----------------
__global__ void __launch_bounds__(1024) scan2_kernel(
    const uint32_t* __restrict__ bsum, uint32_t* __restrict__ boff, int nb) {
  __shared__ uint32_t sm[1024];
  int t = threadIdx.x;
  uint32_t s = (t < nb) ? bsum[t] : 0u;
  sm[t] = s;
  uint32_t v = s;
  __syncthreads();
  #pragma unroll
  for (int off = 1; off < 1024; off <<= 1) {
    uint32_t u = (t >= off) ? sm[t - off] : 0u;
    __syncthreads();
    v += u;
    sm[t] = v;
    __syncthreads();
  }
  if (t < nb) boff[t] = v - s;
}

// ---------------- CSR fill: no atomics (pos precomputed) --------------------
__global__ void __launch_bounds__(256) fill_kernel(
    const int* __restrict__ src, const int* __restrict__ dst,
    const float* __restrict__ ew, const uint32_t* __restrict__ partial,
    const uint32_t* __restrict__ boff, const uint32_t* __restrict__ pos,
    uint2* __restrict__ pairs, int E) {
  int e = blockIdx.x * 256 + threadIdx.x;
  if (e < E) {
    int d = dst[e];
    union { float f; uint32_t u; } w; w.f = ew[e];
    pairs[partial[d] + boff[d >> 10] + pos[e]] = make_uint2((uint32_t)src[e], w.u);
  }
}

// ---------------- Gather (bf16 rows, 4 edges/iter) + normalize --------------
__global__ void __launch_bounds__(256) gather_kernel(
    const uint2* __restrict__ pairs, const uint32_t* __restrict__ partial,
    const uint32_t* __restrict__ boff, const uint32_t* __restrict__ deg,
    uint32_t* __restrict__ cat, int N) {
  int n = blockIdx.x * 4 + (threadIdx.x >> 6);
  if (n >= N) return;
  int lane = threadIdx.x & 63;
  int sg = lane >> 4;   // edge slot within iteration
  int sl = lane & 15;   // element slot: elems 8*sl .. 8*sl+7
  uint32_t base = partial[n] + boff[n >> 10];
  int dn = (int)deg[n];

  uint2 mp = (lane < dn) ? pairs[base + lane] : make_uint2(0u, 0u);

  float a[8] = {0.f, 0.f, 0.f, 0.f, 0.f, 0.f, 0.f, 0.f};
  int iters = (dn + 3) >> 2;
  for (int i = 0; i < iters; ++i) {
    int k = i * 4 + sg;
    uint32_t su = (uint32_t)__shfl((int)mp.x, k, 64);
    uint32_t wu = (uint32_t)__shfl((int)mp.y, k, 64);
    if (k < dn) {
      union { uint32_t u; float f; } w; w.u = wu;
      uint4 v = reinterpret_cast<const uint4*>(cat + (size_t)su * 128)[sl];
      a[0] += w.f * bflo(v.x); a[1] += w.f * bfhi(v.x);
      a[2] += w.f * bflo(v.y); a[3] += w.f * bfhi(v.y);
      a[4] += w.f * bflo(v.z); a[5] += w.f * bfhi(v.z);
      a[6] += w.f * bflo(v.w); a[7] += w.f * bfhi(v.w);
    }
  }
  // correctness tail for deg > 64 (statistically never taken here)
  for (int k = 64 + sg; k < dn; k += 4) {
    uint2 p = pairs[base + k];
    union { uint32_t u; float f; } w; w.u = p.y;
    uint4 v = reinterpret_cast<const uint4*>(cat + (size_t)p.x * 128)[sl];
    a[0] += w.f * bflo(v.x); a[1] += w.f * bfhi(v.x);
    a[2] += w.f * bflo(v.y); a[3] += w.f * bfhi(v.y);
    a[4] += w.f * bflo(v.z); a[5] += w.f * bfhi(v.z);
    a[6] += w.f * bflo(v.w); a[7] += w.f * bfhi(v.w);
  }

  #pragma unroll
  for (int j = 0; j < 8; ++j) {
    a[j] += __shfl_xor(a[j], 16, 64);
    a[j] += __shfl_xor(a[j], 32, 64);
  }
  float ss = 0.f;
  #pragma unroll
  for (int j = 0; j < 8; ++j) ss += a[j] * a[j];
  ss += __shfl_xor(ss, 1, 64);
  ss += __shfl_xor(ss, 2, 64);
  ss += __shfl_xor(ss, 4, 64);
  ss += __shfl_xor(ss, 8, 64);
  float scale = 1.0f / fmaxf(sqrtf(ss), 1e-12f);
  if (lane < 16) {
    uint4 o;
    o.x = pack2bf(a[0] * scale, a[1] * scale);
    o.y = pack2bf(a[2] * scale, a[3] * scale);
    o.z = pack2bf(a[4] * scale, a[5] * scale);
    o.w = pack2bf(a[6] * scale, a[7] * scale);
    reinterpret_cast<uint4*>(cat + (size_t)n * 128 + 64)[sl] = o;
  }
}

// ---------------- out = normalize(cat @ W^T + b) ----------------------------
// 8 waves/block; wave w holds the W panel for columns [w*16, w*16+16) in
// registers (8 KB = 32 VGPR, loaded once). Per 16-node tile: 8 A-loads +
// 8 MFMA; row-norm via tiny cross-wave LDS reduction (double-buffered).
__global__ void __launch_bounds__(512) gemm_kernel(
    const ushort* __restrict__ cat, const ushort* __restrict__ Wb,
    const float* __restrict__ bias, float* __restrict__ out, int N) {
  __shared__ float sP[2][8][16];
  int t = threadIdx.x;
  int wid = t >> 6;      // column tile owned by this wave
  int lane = t & 63;
  int c = lane & 15;     // col within tile / A row within node tile
  int kg = lane >> 4;

  short8 b[8];
  {
    const ushort* wrow = Wb + (size_t)(wid * 16 + c) * 256 + kg * 8;
    #pragma unroll
    for (int ks = 0; ks < 8; ++ks)
      b[ks] = *reinterpret_cast<const short8*>(wrow + ks * 32);
  }
  float bv = bias[wid * 16 + c];

  int ntiles = (N + 15) >> 4;
  int par = 0;
  int tile = blockIdx.x;
  short8 a[8];
  if (tile < ntiles) {
    int rw = min(tile * 16 + c, N - 1);
    const ushort* arow = cat + (size_t)rw * 256 + kg * 8;
    #pragma unroll
    for (int ks = 0; ks < 8; ++ks)
      a[ks] = *reinterpret_cast<const short8*>(arow + ks * 32);
  }

  for (; tile < ntiles; tile += gridDim.x) {
    // prefetch next tile's A while computing this one
    short8 an[8];
    int tn = tile + gridDim.x;
    if (tn < ntiles) {
      int rw = min(tn * 16 + c, N - 1);
      const ushort* arow = cat + (size_t)rw * 256 + kg * 8;
      #pragma unroll
      for (int ks = 0; ks < 8; ++ks)
        an[ks] = *reinterpret_cast<const short8*>(arow + ks * 32);
    }

    f32x4 acc = (f32x4){0.f, 0.f, 0.f, 0.f};
    #pragma unroll
    for (int ks = 0; ks < 8; ++ks)
      acc = __builtin_amdgcn_mfma_f32_16x16x32_bf16(a[ks], b[ks], acc, 0, 0, 0);

    // bias + per-row partial sum of squares (reduce over this wave's 16 cols)
    #pragma unroll
    for (int reg = 0; reg < 4; ++reg) {
      float v = acc[reg] + bv;
      acc[reg] = v;
      float ssp = v * v;
      ssp += __shfl_xor(ssp, 1, 64);
      ssp += __shfl_xor(ssp, 2, 64);
      ssp += __shfl_xor(ssp, 4, 64);
      ssp += __shfl_xor(ssp, 8, 64);
      if (c == 0) sP[par][wid][kg * 4 + reg] = ssp;
    }
    __syncthreads();

    int node0 = tile * 16;
    #pragma unroll
    for (int reg = 0; reg < 4; ++reg) {
      int row = kg * 4 + reg;
      float tot = 0.f;
      #pragma unroll
      for (int w = 0; w < 8; ++w) tot += sP[par][w][row];
      float scale = 1.0f / fmaxf(sqrtf(tot), 1e-12f);
      if (node0 + row < N)
        out[(size_t)(node0 + row) * 128 + wid * 16 + c] = acc[reg] * scale;
    }
    par ^= 1;
    #pragma unroll
    for (int ks = 0; ks < 8; ++ks) a[ks] = an[ks];
  }
}

extern "C" void kernel_launch(void* const* d_in, const int* in_sizes, int n_in,
                              void* d_out, int out_size, void* d_ws, size_t ws_size,
                              hipStream_t stream) {
  const float* x    = (const float*)d_in[0];
  const int*   ei   = (const int*)d_in[1];   // [2, E]: row0 = src, row1 = dst
  const float* ew   = (const float*)d_in[2];
  const float* W    = (const float*)d_in[3];
  const float* bias = (const float*)d_in[4];
  float* out = (float*)d_out;

  int N = in_sizes[0] / 128;
  int E = in_sizes[1] / 2;
  const int* src = ei;
  const int* dst = ei + E;
  int nb = (N + 1023) / 1024;

  // d_ws: bf16 cat [N][256] (N*128 u32), then bf16 W (16384 u32)
  uint32_t* cat = (uint32_t*)d_ws;
  uint32_t* Wb  = cat + (size_t)N * 128;

  // CSR scratch in d_out (free until gemm overwrites d_out):
  // deg[N], partial[N], bsum[1024], boff[1024], pairs[E](uint2), pos[E]
  uint32_t* o       = (uint32_t*)d_out;
  uint32_t* deg     = o;
  uint32_t* partial = o + N;
  uint32_t* bsum    = o + 2 * (size_t)N;
  uint32_t* boff    = o + 2 * (size_t)N + 1024;
  uint2*    pairs   = (uint2*)(o + 2 * (size_t)N + 2048);
  uint32_t* pos     = o + 2 * (size_t)N + 2048 + 2 * (size_t)E;

  int cB = (E + 255) / 256;
  int xB = (N + 3) / 4;
  hipMemsetAsync(deg, 0, (size_t)N * sizeof(uint32_t), stream);
  prep_kernel<<<cB + xB + 64, 256, 0, stream>>>(dst, deg, pos, x, cat, W, Wb,
                                                E, N, cB, xB);
  scan1_kernel<<<nb, 256, 0, stream>>>(deg, partial, bsum, N);
  scan2_kernel<<<1, 1024, 0, stream>>>(bsum, boff, nb);
  fill_kernel<<<(E + 255) / 256, 256, 0, stream>>>(src, dst, ew, partial, boff,
                                                   pos, pairs, E);
  gather_kernel<<<(N + 3) / 4, 256, 0, stream>>>(pairs, partial, boff, deg, cat, N);
  int ntiles16 = (N + 15) / 16;
  int g = ntiles16 < 1024 ? ntiles16 : 1024;
  gemm_kernel<<<g, 512, 0, stream>>>(
      (const ushort*)cat, (const ushort*)Wb, bias, out, N);
}

// Round 10
// 146.714 us; speedup vs baseline: 1.1371x; 1.1371x over previous
//
#include <hip/hip_runtime.h>
#include <stdint.h>

typedef __attribute__((ext_vector_type(8))) short short8;
typedef __attribute__((ext_vector_type(4))) float f32x4;

__device__ __forceinline__ uint32_t f2bf1(float f) {
  union { float f; uint32_t u; } c; c.f = f;
  return (c.u + 0x7FFFu + ((c.u >> 16) & 1u)) >> 16;
}
__device__ __forceinline__ uint32_t pack2bf(float lo, float hi) {
  return f2bf1(lo) | (f2bf1(hi) << 16);
}
__device__ __forceinline__ float bflo(uint32_t u) {
  union { uint32_t u; float f; } c; c.u = u << 16; return c.f;
}
__device__ __forceinline__ float bfhi(uint32_t u) {
  union { uint32_t u; float f; } c; c.u = u & 0xFFFF0000u; return c.f;
}

// Fragment layout: frag chunk (tile16 t, ks, lane) holds node t*16+(lane&15),
// cols ks*32 + (lane>>4)*8 .. +8 (8 bf16 = one uint4). One wave's load of a
// whole A/B fragment is a single contiguous 1KB burst.

// ---- prep: [0,cB) count+pos | [cB,cB+xB) xbf row-major | then catf-x | wf --
__global__ void __launch_bounds__(256) prep_kernel(
    const int* __restrict__ dst, uint32_t* __restrict__ deg,
    uint32_t* __restrict__ pos,
    const float* __restrict__ x, uint32_t* __restrict__ xbf,
    uint32_t* __restrict__ catf,
    const float* __restrict__ W, uint32_t* __restrict__ wf,
    int E, int N, int cB, int xB, int fB) {
  int b = blockIdx.x;
  int ti = threadIdx.x;
  if (b < cB) {
    int e = b * 256 + ti;
    if (e < E) pos[e] = atomicAdd(&deg[dst[e]], 1u);
  } else if (b < cB + xB) {
    int n = (b - cB) * 4 + (ti >> 6);
    if (n >= N) return;
    int lane = ti & 63;
    float2 xv = reinterpret_cast<const float2*>(x + (size_t)n * 128)[lane];
    xbf[(size_t)n * 64 + lane] = pack2bf(xv.x, xv.y);
  } else if (b < cB + xB + fB) {
    int t = b - cB - xB;                 // 16-node tile
    int ks = ti >> 6;                    // 0..3 (x covers ks 0..3)
    int lane = ti & 63;
    int node = t * 16 + (lane & 15);
    const float* xp = x + (size_t)node * 128 + ks * 32 + (lane >> 4) * 8;
    float4 f0 = reinterpret_cast<const float4*>(xp)[0];
    float4 f1 = reinterpret_cast<const float4*>(xp)[1];
    uint4 pk;
    pk.x = pack2bf(f0.x, f0.y); pk.y = pack2bf(f0.z, f0.w);
    pk.z = pack2bf(f1.x, f1.y); pk.w = pack2bf(f1.z, f1.w);
    reinterpret_cast<uint4*>(catf)[(size_t)(t * 8 + ks) * 64 + lane] = pk;
  } else {
    int ch = (b - cB - xB - fB) * 256 + ti;   // W frag chunk id
    if (ch < 4096) {
      int nt = ch >> 9, ks = (ch >> 6) & 7, lane = ch & 63;
      int row = nt * 16 + (lane & 15);
      const float* wp = W + (size_t)row * 256 + ks * 32 + (lane >> 4) * 8;
      float4 f0 = reinterpret_cast<const float4*>(wp)[0];
      float4 f1 = reinterpret_cast<const float4*>(wp)[1];
      uint4 pk;
      pk.x = pack2bf(f0.x, f0.y); pk.y = pack2bf(f0.z, f0.w);
      pk.z = pack2bf(f1.x, f1.y); pk.w = pack2bf(f1.z, f1.w);
      reinterpret_cast<uint4*>(wf)[ch] = pk;
    }
  }
}

// ---------------- scan stage 1: per-1024-chunk exclusive partials -----------
__global__ void __launch_bounds__(256) scan1_kernel(
    const uint32_t* __restrict__ deg, uint32_t* __restrict__ partial,
    uint32_t* __restrict__ bsum, int N) {
  __shared__ uint32_t sm[256];
  int t = threadIdx.x;
  int base = blockIdx.x * 1024 + t * 4;
  uint32_t d0 = 0, d1 = 0, d2 = 0, d3 = 0;
  if (base + 3 < N) {
    uint4 v = *reinterpret_cast<const uint4*>(deg + base);
    d0 = v.x; d1 = v.y; d2 = v.z; d3 = v.w;
  } else {
    if (base + 0 < N) d0 = deg[base + 0];
    if (base + 1 < N) d1 = deg[base + 1];
    if (base + 2 < N) d2 = deg[base + 2];
    if (base + 3 < N) d3 = deg[base + 3];
  }
  uint32_t s4 = d0 + d1 + d2 + d3;
  sm[t] = s4;
  uint32_t v = s4;
  __syncthreads();
  #pragma unroll
  for (int off = 1; off < 256; off <<= 1) {
    uint32_t u = (t >= off) ? sm[t - off] : 0u;
    __syncthreads();
    v += u;
    sm[t] = v;
    __syncthreads();
  }
  uint32_t ex = v - s4;
  if (base + 0 < N) partial[base + 0] = ex;
  if (base + 1 < N) partial[base + 1] = ex + d0;
  if (base + 2 < N) partial[base + 2] = ex + d0 + d1;
  if (base + 3 < N) partial[base + 3] = ex + d0 + d1 + d2;
  if (t == 255) bsum[blockIdx.x] = v;
}

// ---------------- scan stage 2: exclusive scan of block sums ----------------
__global__ void __launch_bounds__(1024) scan2_kernel(
    const uint32_t* __restrict__ bsum, uint32_t* __restrict__ boff, int nb) {
  __shared__ uint32_t sm[1024];
  int t = threadIdx.x;
  uint32_t s = (t < nb) ? bsum[t] : 0u;
  sm[t] = s;
  uint32_t v = s;
  __syncthreads();
  #pragma unroll
  for (int off = 1; off < 1024; off <<= 1) {
    uint32_t u = (t >= off) ? sm[t - off] : 0u;
    __syncthreads();
    v += u;
    sm[t] = v;
    __syncthreads();
  }
  if (t < nb) boff[t] = v - s;
}

// ---------------- CSR fill: no atomics (pos precomputed) --------------------
__global__ void __launch_bounds__(256) fill_kernel(
    const int* __restrict__ src, const int* __restrict__ dst,
    const float* __restrict__ ew, const uint32_t* __restrict__ partial,
    const uint32_t* __restrict__ boff, const uint32_t* __restrict__ pos,
    uint2* __restrict__ pairs, int E) {
  int e = blockIdx.x * 256 + threadIdx.x;
  if (e < E) {
    int d = dst[e];
    union { float f; uint32_t u; } w; w.f = ew[e];
    pairs[partial[d] + boff[d >> 10] + pos[e]] = make_uint2((uint32_t)src[e], w.u);
  }
}

// ------- Gather (row-major bf16 x reads) + normalize + frag-major write -----
__global__ void __launch_bounds__(256) gather_kernel(
    const uint2* __restrict__ pairs, const uint32_t* __restrict__ partial,
    const uint32_t* __restrict__ boff, const uint32_t* __restrict__ deg,
    const uint32_t* __restrict__ xbf, uint32_t* __restrict__ catf, int N) {
  int n = blockIdx.x * 4 + (threadIdx.x >> 6);
  if (n >= N) return;
  int lane = threadIdx.x & 63;
  int sg = lane >> 4;   // edge slot within iteration
  int sl = lane & 15;   // element slot: elems 8*sl .. 8*sl+7
  uint32_t base = partial[n] + boff[n >> 10];
  int dn = (int)deg[n];

  uint2 mp = (lane < dn) ? pairs[base + lane] : make_uint2(0u, 0u);

  float a[8] = {0.f, 0.f, 0.f, 0.f, 0.f, 0.f, 0.f, 0.f};
  int iters = (dn + 3) >> 2;
  for (int i = 0; i < iters; ++i) {
    int k = i * 4 + sg;
    uint32_t su = (uint32_t)__shfl((int)mp.x, k, 64);
    uint32_t wu = (uint32_t)__shfl((int)mp.y, k, 64);
    if (k < dn) {
      union { uint32_t u; float f; } w; w.u = wu;
      uint4 v = reinterpret_cast<const uint4*>(xbf + (size_t)su * 64)[sl];
      a[0] += w.f * bflo(v.x); a[1] += w.f * bfhi(v.x);
      a[2] += w.f * bflo(v.y); a[3] += w.f * bfhi(v.y);
      a[4] += w.f * bflo(v.z); a[5] += w.f * bfhi(v.z);
      a[6] += w.f * bflo(v.w); a[7] += w.f * bfhi(v.w);
    }
  }
  // correctness tail for deg > 64 (statistically never taken here)
  for (int k = 64 + sg; k < dn; k += 4) {
    uint2 p = pairs[base + k];
    union { uint32_t u; float f; } w; w.u = p.y;
    uint4 v = reinterpret_cast<const uint4*>(xbf + (size_t)p.x * 64)[sl];
    a[0] += w.f * bflo(v.x); a[1] += w.f * bfhi(v.x);
    a[2] += w.f * bflo(v.y); a[3] += w.f * bfhi(v.y);
    a[4] += w.f * bflo(v.z); a[5] += w.f * bfhi(v.z);
    a[6] += w.f * bflo(v.w); a[7] += w.f * bfhi(v.w);
  }

  #pragma unroll
  for (int j = 0; j < 8; ++j) {
    a[j] += __shfl_xor(a[j], 16, 64);
    a[j] += __shfl_xor(a[j], 32, 64);
  }
  float ss = 0.f;
  #pragma unroll
  for (int j = 0; j < 8; ++j) ss += a[j] * a[j];
  ss += __shfl_xor(ss, 1, 64);
  ss += __shfl_xor(ss, 2, 64);
  ss += __shfl_xor(ss, 4, 64);
  ss += __shfl_xor(ss, 8, 64);
  float scale = 1.0f / fmaxf(sqrtf(ss), 1e-12f);
  if (lane < 16) {
    uint4 o;
    o.x = pack2bf(a[0] * scale, a[1] * scale);
    o.y = pack2bf(a[2] * scale, a[3] * scale);
    o.z = pack2bf(a[4] * scale, a[5] * scale);
    o.w = pack2bf(a[6] * scale, a[7] * scale);
    // ng cols 128+8*sl..+8 -> frag (t, ks=4+(sl>>2), lane=(sl&3)*16+rr)
    int t = n >> 4, rr = n & 15;
    reinterpret_cast<uint4*>(catf)[
        (size_t)(t * 8 + 4 + (sl >> 2)) * 64 + (sl & 3) * 16 + rr] = o;
  }
}

// ---------------- out = normalize(cat @ W^T + b), frag-major loads ----------
// One wave per 32-node tile (two 16-row subtiles sharing each B-frag load).
// Every A/B fragment load is one contiguous 1KB burst.
__global__ void __launch_bounds__(256) gemm_kernel(
    const uint32_t* __restrict__ catf, const uint32_t* __restrict__ wf,
    const float* __restrict__ bias, float* __restrict__ out, int N) {
  int wid = threadIdx.x >> 6;
  int lane = threadIdx.x & 63;
  int tile = blockIdx.x * 4 + wid;     // 32-row tile
  int node0 = tile * 32;
  if (node0 >= N) return;
  int r = lane & 15;
  int kg = lane >> 4;
  int t0 = tile * 2;                   // 16-row frag tiles t0, t0+1

  short8 a0[8], a1[8];
  #pragma unroll
  for (int ks = 0; ks < 8; ++ks) {
    a0[ks] = *reinterpret_cast<const short8*>(
        catf + ((size_t)(t0 * 8 + ks) * 64 + lane) * 4);
    a1[ks] = *reinterpret_cast<const short8*>(
        catf + ((size_t)((t0 + 1) * 8 + ks) * 64 + lane) * 4);
  }

  f32x4 acc0[8], acc1[8];
  #pragma unroll
  for (int nt = 0; nt < 8; ++nt) {
    acc0[nt] = (f32x4){0.f, 0.f, 0.f, 0.f};
    acc1[nt] = (f32x4){0.f, 0.f, 0.f, 0.f};
  }

  #pragma unroll
  for (int nt = 0; nt < 8; ++nt) {
    #pragma unroll
    for (int ks = 0; ks < 8; ++ks) {
      short8 bfrag = *reinterpret_cast<const short8*>(
          wf + ((size_t)(nt * 8 + ks) * 64 + lane) * 4);
      acc0[nt] = __builtin_amdgcn_mfma_f32_16x16x32_bf16(a0[ks], bfrag, acc0[nt], 0, 0, 0);
      acc1[nt] = __builtin_amdgcn_mfma_f32_16x16x32_bf16(a1[ks], bfrag, acc1[nt], 0, 0, 0);
    }
  }

  float bv[8];
  #pragma unroll
  for (int nt = 0; nt < 8; ++nt) bv[nt] = bias[nt * 16 + r];

  #pragma unroll
  for (int st = 0; st < 2; ++st) {
    f32x4* acc = st ? acc1 : acc0;
    int nodeb = node0 + st * 16;
    #pragma unroll
    for (int reg = 0; reg < 4; ++reg) {
      float ss = 0.f;
      #pragma unroll
      for (int nt = 0; nt < 8; ++nt) {
        float v = acc[nt][reg] + bv[nt];
        acc[nt][reg] = v;
        ss += v * v;
      }
      ss += __shfl_xor(ss, 1, 64);
      ss += __shfl_xor(ss, 2, 64);
      ss += __shfl_xor(ss, 4, 64);
      ss += __shfl_xor(ss, 8, 64);
      float scale = 1.0f / fmaxf(sqrtf(ss), 1e-12f);
      float* orow = out + (size_t)(nodeb + kg * 4 + reg) * 128;
      #pragma unroll
      for (int nt = 0; nt < 8; ++nt)
        orow[nt * 16 + r] = acc[nt][reg] * scale;
    }
  }
}

extern "C" void kernel_launch(void* const* d_in, const int* in_sizes, int n_in,
                              void* d_out, int out_size, void* d_ws, size_t ws_size,
                              hipStream_t stream) {
  const float* x    = (const float*)d_in[0];
  const int*   ei   = (const int*)d_in[1];   // [2, E]: row0 = src, row1 = dst
  const float* ew   = (const float*)d_in[2];
  const float* W    = (const float*)d_in[3];
  const float* bias = (const float*)d_in[4];
  float* out = (float*)d_out;

  int N = in_sizes[0] / 128;
  int E = in_sizes[1] / 2;
  const int* src = ei;
  const int* dst = ei + E;
  int nb = (N + 1023) / 1024;

  // d_ws: frag-major cat (N*128 u32), then frag-major W (16384 u32)
  uint32_t* catf = (uint32_t*)d_ws;
  uint32_t* wf   = catf + (size_t)N * 128;

  // d_out scratch (free until gemm overwrites d_out):
  // deg[N], partial[N], bsum[1024], boff[1024], pairs[E](uint2), pos[E],
  // xbf row-major bf16 x (N*64 u32)
  uint32_t* o       = (uint32_t*)d_out;
  uint32_t* deg     = o;
  uint32_t* partial = o + N;
  uint32_t* bsum    = o + 2 * (size_t)N;
  uint32_t* boff    = o + 2 * (size_t)N + 1024;
  uint2*    pairs   = (uint2*)(o + 2 * (size_t)N + 2048);
  uint32_t* pos     = o + 2 * (size_t)N + 2048 + 2 * (size_t)E;
  uint32_t* xbf     = o + 2 * (size_t)N + 2048 + 3 * (size_t)E;

  int cB = (E + 255) / 256;
  int xB = (N + 3) / 4;
  int fB = (N + 15) / 16;
  hipMemsetAsync(deg, 0, (size_t)N * sizeof(uint32_t), stream);
  prep_kernel<<<cB + xB + fB + 16, 256, 0, stream>>>(
      dst, deg, pos, x, xbf, catf, W, wf, E, N, cB, xB, fB);
  scan1_kernel<<<nb, 256, 0, stream>>>(deg, partial, bsum, N);
  scan2_kernel<<<1, 1024, 0, stream>>>(bsum, boff, nb);
  fill_kernel<<<(E + 255) / 256, 256, 0, stream>>>(src, dst, ew, partial, boff,
                                                   pos, pairs, E);
  gather_kernel<<<(N + 3) / 4, 256, 0, stream>>>(pairs, partial, boff, deg,
                                                 xbf, catf, N);
  int ntiles32 = (N + 31) / 32;
  gemm_kernel<<<(ntiles32 + 3) / 4, 256, 0, stream>>>(catf, wf, bias, out, N);
}

// Round 11
// 139.445 us; speedup vs baseline: 1.1964x; 1.0521x over previous
//
#include <hip/hip_runtime.h>
#include <stdint.h>

typedef __attribute__((ext_vector_type(8))) short short8;
typedef __attribute__((ext_vector_type(4))) float f32x4;

__device__ __forceinline__ uint32_t f2bf1(float f) {
  union { float f; uint32_t u; } c; c.f = f;
  return (c.u + 0x7FFFu + ((c.u >> 16) & 1u)) >> 16;
}
__device__ __forceinline__ uint32_t pack2bf(float lo, float hi) {
  return f2bf1(lo) | (f2bf1(hi) << 16);
}
__device__ __forceinline__ float bflo(uint32_t u) {
  union { uint32_t u; float f; } c; c.u = u << 16; return c.f;
}
__device__ __forceinline__ float bfhi(uint32_t u) {
  union { uint32_t u; float f; } c; c.u = u & 0xFFFF0000u; return c.f;
}

// Fragment layout: frag chunk (tile16 t, ks, lane) holds node t*16+(lane&15),
// cols ks*32 + (lane>>4)*8 .. +8 (8 bf16 = one uint4 = u32s [lane*4..lane*4+3]
// of chunk). One wave's A/B fragment load is a single contiguous 1KB burst.

// ---- prep: [0,cB) count+pos | [cB,cB+xB) x -> xbf(row) + catf(frag) | wf ---
__global__ void __launch_bounds__(256) prep_kernel(
    const int* __restrict__ dst, uint32_t* __restrict__ deg,
    uint32_t* __restrict__ pos,
    const float* __restrict__ x, uint32_t* __restrict__ xbf,
    uint32_t* __restrict__ catf,
    const float* __restrict__ W, uint32_t* __restrict__ wf,
    int E, int N, int cB, int xB) {
  int b = blockIdx.x;
  int ti = threadIdx.x;
  if (b < cB) {
    int e = b * 256 + ti;
    if (e < E) pos[e] = atomicAdd(&deg[dst[e]], 1u);
  } else if (b < cB + xB) {
    int n = (b - cB) * 4 + (ti >> 6);
    if (n >= N) return;
    int l = ti & 63;
    float2 xv = reinterpret_cast<const float2*>(x + (size_t)n * 128)[l];
    uint32_t pk = pack2bf(xv.x, xv.y);
    xbf[(size_t)n * 64 + l] = pk;                       // row-major, coalesced
    // frag-major: cols 2l,2l+1 of node n -> chunk ((n>>4)*8 + (l>>4)),
    // lane_c = ((l>>2)&3)*16 + (n&15), j = l&3
    catf[((size_t)((n >> 4) * 8 + (l >> 4)) * 64 +
          ((l >> 2) & 3) * 16 + (n & 15)) * 4 + (l & 3)] = pk;
  } else {
    int ch = (b - cB - xB) * 256 + ti;   // W frag chunk id
    if (ch < 4096) {
      int nt = ch >> 9, ks = (ch >> 6) & 7, lane = ch & 63;
      int row = nt * 16 + (lane & 15);
      const float* wp = W + (size_t)row * 256 + ks * 32 + (lane >> 4) * 8;
      float4 f0 = reinterpret_cast<const float4*>(wp)[0];
      float4 f1 = reinterpret_cast<const float4*>(wp)[1];
      uint4 pk;
      pk.x = pack2bf(f0.x, f0.y); pk.y = pack2bf(f0.z, f0.w);
      pk.z = pack2bf(f1.x, f1.y); pk.w = pack2bf(f1.z, f1.w);
      reinterpret_cast<uint4*>(wf)[ch] = pk;
    }
  }
}

// ---------------- scan stage 1: per-1024-chunk exclusive partials -----------
__global__ void __launch_bounds__(256) scan1_kernel(
    const uint32_t* __restrict__ deg, uint32_t* __restrict__ partial,
    uint32_t* __restrict__ bsum, int N) {
  __shared__ uint32_t sm[256];
  int t = threadIdx.x;
  int base = blockIdx.x * 1024 + t * 4;
  uint32_t d0 = 0, d1 = 0, d2 = 0, d3 = 0;
  if (base + 3 < N) {
    uint4 v = *reinterpret_cast<const uint4*>(deg + base);
    d0 = v.x; d1 = v.y; d2 = v.z; d3 = v.w;
  } else {
    if (base + 0 < N) d0 = deg[base + 0];
    if (base + 1 < N) d1 = deg[base + 1];
    if (base + 2 < N) d2 = deg[base + 2];
    if (base + 3 < N) d3 = deg[base + 3];
  }
  uint32_t s4 = d0 + d1 + d2 + d3;
  sm[t] = s4;
  uint32_t v = s4;
  __syncthreads();
  #pragma unroll
  for (int off = 1; off < 256; off <<= 1) {
    uint32_t u = (t >= off) ? sm[t - off] : 0u;
    __syncthreads();
    v += u;
    sm[t] = v;
    __syncthreads();
  }
  uint32_t ex = v - s4;
  if (base + 0 < N) partial[base + 0] = ex;
  if (base + 1 < N) partial[base + 1] = ex + d0;
  if (base + 2 < N) partial[base + 2] = ex + d0 + d1;
  if (base + 3 < N) partial[base + 3] = ex + d0 + d1 + d2;
  if (t == 255) bsum[blockIdx.x] = v;
}

// ---------------- scan stage 2: exclusive scan of block sums ----------------
__global__ void __launch_bounds__(1024) scan2_kernel(
    const uint32_t* __restrict__ bsum, uint32_t* __restrict__ boff, int nb) {
  __shared__ uint32_t sm[1024];
  int t = threadIdx.x;
  uint32_t s = (t < nb) ? bsum[t] : 0u;
  sm[t] = s;
  uint32_t v = s;
  __syncthreads();
  #pragma unroll
  for (int off = 1; off < 1024; off <<= 1) {
    uint32_t u = (t >= off) ? sm[t - off] : 0u;
    __syncthreads();
    v += u;
    sm[t] = v;
    __syncthreads();
  }
  if (t < nb) boff[t] = v - s;
}

// ---------------- CSR fill: no atomics (pos precomputed) --------------------
__global__ void __launch_bounds__(256) fill_kernel(
    const int* __restrict__ src, const int* __restrict__ dst,
    const float* __restrict__ ew, const uint32_t* __restrict__ partial,
    const uint32_t* __restrict__ boff, const uint32_t* __restrict__ pos,
    uint2* __restrict__ pairs, int E) {
  int e = blockIdx.x * 256 + threadIdx.x;
  if (e < E) {
    int d = dst[e];
    union { float f; uint32_t u; } w; w.f = ew[e];
    pairs[partial[d] + boff[d >> 10] + pos[e]] = make_uint2((uint32_t)src[e], w.u);
  }
}

// ------- Gather (row-major bf16 x reads) + normalize + frag-major write -----
__global__ void __launch_bounds__(256) gather_kernel(
    const uint2* __restrict__ pairs, const uint32_t* __restrict__ partial,
    const uint32_t* __restrict__ boff, const uint32_t* __restrict__ deg,
    const uint32_t* __restrict__ xbf, uint32_t* __restrict__ catf, int N) {
  int n = blockIdx.x * 4 + (threadIdx.x >> 6);
  if (n >= N) return;
  int lane = threadIdx.x & 63;
  int sg = lane >> 4;   // edge slot within iteration
  int sl = lane & 15;   // element slot: elems 8*sl .. 8*sl+7
  uint32_t base = partial[n] + boff[n >> 10];
  int dn = (int)deg[n];

  uint2 mp = (lane < dn) ? pairs[base + lane] : make_uint2(0u, 0u);

  float a[8] = {0.f, 0.f, 0.f, 0.f, 0.f, 0.f, 0.f, 0.f};
  int iters = (dn + 3) >> 2;
  for (int i = 0; i < iters; ++i) {
    int k = i * 4 + sg;
    uint32_t su = (uint32_t)__shfl((int)mp.x, k, 64);
    uint32_t wu = (uint32_t)__shfl((int)mp.y, k, 64);
    if (k < dn) {
      union { uint32_t u; float f; } w; w.u = wu;
      uint4 v = reinterpret_cast<const uint4*>(xbf + (size_t)su * 64)[sl];
      a[0] += w.f * bflo(v.x); a[1] += w.f * bfhi(v.x);
      a[2] += w.f * bflo(v.y); a[3] += w.f * bfhi(v.y);
      a[4] += w.f * bflo(v.z); a[5] += w.f * bfhi(v.z);
      a[6] += w.f * bflo(v.w); a[7] += w.f * bfhi(v.w);
    }
  }
  // correctness tail for deg > 64 (statistically never taken here)
  for (int k = 64 + sg; k < dn; k += 4) {
    uint2 p = pairs[base + k];
    union { uint32_t u; float f; } w; w.u = p.y;
    uint4 v = reinterpret_cast<const uint4*>(xbf + (size_t)p.x * 64)[sl];
    a[0] += w.f * bflo(v.x); a[1] += w.f * bfhi(v.x);
    a[2] += w.f * bflo(v.y); a[3] += w.f * bfhi(v.y);
    a[4] += w.f * bflo(v.z); a[5] += w.f * bfhi(v.z);
    a[6] += w.f * bflo(v.w); a[7] += w.f * bfhi(v.w);
  }

  #pragma unroll
  for (int j = 0; j < 8; ++j) {
    a[j] += __shfl_xor(a[j], 16, 64);
    a[j] += __shfl_xor(a[j], 32, 64);
  }
  float ss = 0.f;
  #pragma unroll
  for (int j = 0; j < 8; ++j) ss += a[j] * a[j];
  ss += __shfl_xor(ss, 1, 64);
  ss += __shfl_xor(ss, 2, 64);
  ss += __shfl_xor(ss, 4, 64);
  ss += __shfl_xor(ss, 8, 64);
  float scale = 1.0f / fmaxf(sqrtf(ss), 1e-12f);
  if (lane < 16) {
    uint4 o;
    o.x = pack2bf(a[0] * scale, a[1] * scale);
    o.y = pack2bf(a[2] * scale, a[3] * scale);
    o.z = pack2bf(a[4] * scale, a[5] * scale);
    o.w = pack2bf(a[6] * scale, a[7] * scale);
    // ng cols 128+8*sl..+8 -> frag (t, ks=4+(sl>>2), lane=(sl&3)*16+rr)
    int t = n >> 4, rr = n & 15;
    reinterpret_cast<uint4*>(catf)[
        (size_t)(t * 8 + 4 + (sl >> 2)) * 64 + (sl & 3) * 16 + rr] = o;
  }
}

// ---------------- out = normalize(cat @ W^T + b), frag-major loads ----------
// One wave per 32-node tile (two 16-row subtiles sharing each B-frag load).
__global__ void __launch_bounds__(256) gemm_kernel(
    const uint32_t* __restrict__ catf, const uint32_t* __restrict__ wf,
    const float* __restrict__ bias, float* __restrict__ out, int N) {
  int wid = threadIdx.x >> 6;
  int lane = threadIdx.x & 63;
  int tile = blockIdx.x * 4 + wid;     // 32-row tile
  int node0 = tile * 32;
  if (node0 >= N) return;
  int r = lane & 15;
  int kg = lane >> 4;
  int t0 = tile * 2;                   // 16-row frag tiles t0, t0+1

  short8 a0[8], a1[8];
  #pragma unroll
  for (int ks = 0; ks < 8; ++ks) {
    a0[ks] = *reinterpret_cast<const short8*>(
        catf + ((size_t)(t0 * 8 + ks) * 64 + lane) * 4);
    a1[ks] = *reinterpret_cast<const short8*>(
        catf + ((size_t)((t0 + 1) * 8 + ks) * 64 + lane) * 4);
  }

  f32x4 acc0[8], acc1[8];
  #pragma unroll
  for (int nt = 0; nt < 8; ++nt) {
    acc0[nt] = (f32x4){0.f, 0.f, 0.f, 0.f};
    acc1[nt] = (f32x4){0.f, 0.f, 0.f, 0.f};
  }

  #pragma unroll
  for (int nt = 0; nt < 8; ++nt) {
    #pragma unroll
    for (int ks = 0; ks < 8; ++ks) {
      short8 bfrag = *reinterpret_cast<const short8*>(
          wf + ((size_t)(nt * 8 + ks) * 64 + lane) * 4);
      acc0[nt] = __builtin_amdgcn_mfma_f32_16x16x32_bf16(a0[ks], bfrag, acc0[nt], 0, 0, 0);
      acc1[nt] = __builtin_amdgcn_mfma_f32_16x16x32_bf16(a1[ks], bfrag, acc1[nt], 0, 0, 0);
    }
  }

  float bv[8];
  #pragma unroll
  for (int nt = 0; nt < 8; ++nt) bv[nt] = bias[nt * 16 + r];

  #pragma unroll
  for (int st = 0; st < 2; ++st) {
    f32x4* acc = st ? acc1 : acc0;
    int nodeb = node0 + st * 16;
    #pragma unroll
    for (int reg = 0; reg < 4; ++reg) {
      float ss = 0.f;
      #pragma unroll
      for (int nt = 0; nt < 8; ++nt) {
        float v = acc[nt][reg] + bv[nt];
        acc[nt][reg] = v;
        ss += v * v;
      }
      ss += __shfl_xor(ss, 1, 64);
      ss += __shfl_xor(ss, 2, 64);
      ss += __shfl_xor(ss, 4, 64);
      ss += __shfl_xor(ss, 8, 64);
      float scale = 1.0f / fmaxf(sqrtf(ss), 1e-12f);
      float* orow = out + (size_t)(nodeb + kg * 4 + reg) * 128;
      #pragma unroll
      for (int nt = 0; nt < 8; ++nt)
        orow[nt * 16 + r] = acc[nt][reg] * scale;
    }
  }
}

extern "C" void kernel_launch(void* const* d_in, const int* in_sizes, int n_in,
                              void* d_out, int out_size, void* d_ws, size_t ws_size,
                              hipStream_t stream) {
  const float* x    = (const float*)d_in[0];
  const int*   ei   = (const int*)d_in[1];   // [2, E]: row0 = src, row1 = dst
  const float* ew   = (const float*)d_in[2];
  const float* W    = (const float*)d_in[3];
  const float* bias = (const float*)d_in[4];
  float* out = (float*)d_out;

  int N = in_sizes[0] / 128;
  int E = in_sizes[1] / 2;
  const int* src = ei;
  const int* dst = ei + E;
  int nb = (N + 1023) / 1024;

  // d_ws: frag-major cat (N*128 u32), then frag-major W (16384 u32)
  uint32_t* catf = (uint32_t*)d_ws;
  uint32_t* wf   = catf + (size_t)N * 128;

  // d_out scratch (free until gemm overwrites d_out):
  // deg[N], partial[N], bsum[1024], boff[1024], pairs[E](uint2), pos[E],
  // xbf row-major bf16 x (N*64 u32)
  uint32_t* o       = (uint32_t*)d_out;
  uint32_t* deg     = o;
  uint32_t* partial = o + N;
  uint32_t* bsum    = o + 2 * (size_t)N;
  uint32_t* boff    = o + 2 * (size_t)N + 1024;
  uint2*    pairs   = (uint2*)(o + 2 * (size_t)N + 2048);
  uint32_t* pos     = o + 2 * (size_t)N + 2048 + 2 * (size_t)E;
  uint32_t* xbf     = o + 2 * (size_t)N + 2048 + 3 * (size_t)E;

  int cB = (E + 255) / 256;
  int xB = (N + 3) / 4;
  hipMemsetAsync(deg, 0, (size_t)N * sizeof(uint32_t), stream);
  prep_kernel<<<cB + xB + 16, 256, 0, stream>>>(
      dst, deg, pos, x, xbf, catf, W, wf, E, N, cB, xB);
  scan1_kernel<<<nb, 256, 0, stream>>>(deg, partial, bsum, N);
  scan2_kernel<<<1, 1024, 0, stream>>>(bsum, boff, nb);
  fill_kernel<<<(E + 255) / 256, 256, 0, stream>>>(src, dst, ew, partial, boff,
                                                   pos, pairs, E);
  gather_kernel<<<(N + 3) / 4, 256, 0, stream>>>(pairs, partial, boff, deg,
                                                 xbf, catf, N);
  int ntiles32 = (N + 31) / 32;
  gemm_kernel<<<(ntiles32 + 3) / 4, 256, 0, stream>>>(catf, wf, bias, out, N);
}

// Round 12
// 139.377 us; speedup vs baseline: 1.1970x; 1.0005x over previous
//
#include <hip/hip_runtime.h>
#include <stdint.h>

typedef __attribute__((ext_vector_type(8))) short short8;
typedef __attribute__((ext_vector_type(4))) float f32x4;

__device__ __forceinline__ uint32_t f2bf1(float f) {
  union { float f; uint32_t u; } c; c.f = f;
  return (c.u + 0x7FFFu + ((c.u >> 16) & 1u)) >> 16;
}
__device__ __forceinline__ uint32_t pack2bf(float lo, float hi) {
  return f2bf1(lo) | (f2bf1(hi) << 16);
}
__device__ __forceinline__ float bflo(uint32_t u) {
  union { uint32_t u; float f; } c; c.u = u << 16; return c.f;
}
__device__ __forceinline__ float bfhi(uint32_t u) {
  union { uint32_t u; float f; } c; c.u = u & 0xFFFF0000u; return c.f;
}

// Fragment layout: frag chunk (tile16 t, ks, lane) holds node t*16+(lane&15),
// cols ks*32 + (lane>>4)*8 .. +8 (8 bf16 = one uint4 = u32s [lane*4..lane*4+3]
// of chunk). One wave's A/B fragment load is a single contiguous 1KB burst.

// ---- prep: [0,eB) count+pos x4 | [eB,eB+xB) x->xbf+catf (8 rows/wave) | wf -
__global__ void __launch_bounds__(256) prep_kernel(
    const int* __restrict__ dst, uint32_t* __restrict__ deg,
    uint32_t* __restrict__ pos,
    const float* __restrict__ x, uint32_t* __restrict__ xbf,
    uint32_t* __restrict__ catf,
    const float* __restrict__ W, uint32_t* __restrict__ wf,
    int E, int N, int eB, int xB) {
  int b = blockIdx.x;
  int ti = threadIdx.x;
  if (b < eB) {
    int e4 = (b * 256 + ti) * 4;
    if (e4 + 3 < E) {
      int4 d4 = *reinterpret_cast<const int4*>(dst + e4);
      uint4 p;
      p.x = atomicAdd(&deg[d4.x], 1u);
      p.y = atomicAdd(&deg[d4.y], 1u);
      p.z = atomicAdd(&deg[d4.z], 1u);
      p.w = atomicAdd(&deg[d4.w], 1u);
      *reinterpret_cast<uint4*>(pos + e4) = p;
    } else {
      for (int e = e4; e < E; ++e) pos[e] = atomicAdd(&deg[dst[e]], 1u);
    }
  } else if (b < eB + xB) {
    int w = ti >> 6;
    int l = ti & 63;
    int n0 = (b - eB) * 32 + w * 8;          // 8 rows per wave
    float2 xv[8];
    #pragma unroll
    for (int i = 0; i < 8; ++i) {
      int n = n0 + i;
      xv[i] = (n < N) ? reinterpret_cast<const float2*>(x + (size_t)n * 128)[l]
                      : make_float2(0.f, 0.f);
    }
    #pragma unroll
    for (int i = 0; i < 8; ++i) {
      int n = n0 + i;
      if (n < N) {
        uint32_t pk = pack2bf(xv[i].x, xv[i].y);
        xbf[(size_t)n * 64 + l] = pk;
        catf[((size_t)((n >> 4) * 8 + (l >> 4)) * 64 +
              ((l >> 2) & 3) * 16 + (n & 15)) * 4 + (l & 3)] = pk;
      }
    }
  } else {
    int ch = (b - eB - xB) * 256 + ti;   // W frag chunk id
    if (ch < 4096) {
      int nt = ch >> 9, ks = (ch >> 6) & 7, lane = ch & 63;
      int row = nt * 16 + (lane & 15);
      const float* wp = W + (size_t)row * 256 + ks * 32 + (lane >> 4) * 8;
      float4 f0 = reinterpret_cast<const float4*>(wp)[0];
      float4 f1 = reinterpret_cast<const float4*>(wp)[1];
      uint4 pk;
      pk.x = pack2bf(f0.x, f0.y); pk.y = pack2bf(f0.z, f0.w);
      pk.z = pack2bf(f1.x, f1.y); pk.w = pack2bf(f1.z, f1.w);
      reinterpret_cast<uint4*>(wf)[ch] = pk;
    }
  }
}

// ---------------- scan stage 1: per-1024-chunk exclusive partials -----------
__global__ void __launch_bounds__(256) scan1_kernel(
    const uint32_t* __restrict__ deg, uint32_t* __restrict__ partial,
    uint32_t* __restrict__ bsum, int N) {
  __shared__ uint32_t sm[256];
  int t = threadIdx.x;
  int base = blockIdx.x * 1024 + t * 4;
  uint32_t d0 = 0, d1 = 0, d2 = 0, d3 = 0;
  if (base + 3 < N) {
    uint4 v = *reinterpret_cast<const uint4*>(deg + base);
    d0 = v.x; d1 = v.y; d2 = v.z; d3 = v.w;
  } else {
    if (base + 0 < N) d0 = deg[base + 0];
    if (base + 1 < N) d1 = deg[base + 1];
    if (base + 2 < N) d2 = deg[base + 2];
    if (base + 3 < N) d3 = deg[base + 3];
  }
  uint32_t s4 = d0 + d1 + d2 + d3;
  sm[t] = s4;
  uint32_t v = s4;
  __syncthreads();
  #pragma unroll
  for (int off = 1; off < 256; off <<= 1) {
    uint32_t u = (t >= off) ? sm[t - off] : 0u;
    __syncthreads();
    v += u;
    sm[t] = v;
    __syncthreads();
  }
  uint32_t ex = v - s4;
  if (base + 0 < N) partial[base + 0] = ex;
  if (base + 1 < N) partial[base + 1] = ex + d0;
  if (base + 2 < N) partial[base + 2] = ex + d0 + d1;
  if (base + 3 < N) partial[base + 3] = ex + d0 + d1 + d2;
  if (t == 255) bsum[blockIdx.x] = v;
}

// ---------------- scan stage 2: exclusive scan of block sums ----------------
__global__ void __launch_bounds__(1024) scan2_kernel(
    const uint32_t* __restrict__ bsum, uint32_t* __restrict__ boff, int nb) {
  __shared__ uint32_t sm[1024];
  int t = threadIdx.x;
  uint32_t s = (t < nb) ? bsum[t] : 0u;
  sm[t] = s;
  uint32_t v = s;
  __syncthreads();
  #pragma unroll
  for (int off = 1; off < 1024; off <<= 1) {
    uint32_t u = (t >= off) ? sm[t - off] : 0u;
    __syncthreads();
    v += u;
    sm[t] = v;
    __syncthreads();
  }
  if (t < nb) boff[t] = v - s;
}

// ---------------- CSR fill: no atomics (pos precomputed) --------------------
__global__ void __launch_bounds__(256) fill_kernel(
    const int* __restrict__ src, const int* __restrict__ dst,
    const float* __restrict__ ew, const uint32_t* __restrict__ partial,
    const uint32_t* __restrict__ boff, const uint32_t* __restrict__ pos,
    uint2* __restrict__ pairs, int E) {
  int e = blockIdx.x * 256 + threadIdx.x;
  if (e < E) {
    int d = dst[e];
    union { float f; uint32_t u; } w; w.f = ew[e];
    pairs[partial[d] + boff[d >> 10] + pos[e]] = make_uint2((uint32_t)src[e], w.u);
  }
}

// ------- Gather (row-major bf16 x reads) + normalize + frag-major write -----
__global__ void __launch_bounds__(256) gather_kernel(
    const uint2* __restrict__ pairs, const uint32_t* __restrict__ partial,
    const uint32_t* __restrict__ boff, const uint32_t* __restrict__ deg,
    const uint32_t* __restrict__ xbf, uint32_t* __restrict__ catf, int N) {
  int n = blockIdx.x * 4 + (threadIdx.x >> 6);
  if (n >= N) return;
  int lane = threadIdx.x & 63;
  int sg = lane >> 4;   // edge slot within iteration
  int sl = lane & 15;   // element slot: elems 8*sl .. 8*sl+7
  uint32_t base = partial[n] + boff[n >> 10];
  int dn = (int)deg[n];

  uint2 mp = (lane < dn) ? pairs[base + lane] : make_uint2(0u, 0u);

  float a[8] = {0.f, 0.f, 0.f, 0.f, 0.f, 0.f, 0.f, 0.f};
  int iters = (dn + 3) >> 2;
  for (int i = 0; i < iters; ++i) {
    int k = i * 4 + sg;
    uint32_t su = (uint32_t)__shfl((int)mp.x, k, 64);
    uint32_t wu = (uint32_t)__shfl((int)mp.y, k, 64);
    if (k < dn) {
      union { uint32_t u; float f; } w; w.u = wu;
      uint4 v = reinterpret_cast<const uint4*>(xbf + (size_t)su * 64)[sl];
      a[0] += w.f * bflo(v.x); a[1] += w.f * bfhi(v.x);
      a[2] += w.f * bflo(v.y); a[3] += w.f * bfhi(v.y);
      a[4] += w.f * bflo(v.z); a[5] += w.f * bfhi(v.z);
      a[6] += w.f * bflo(v.w); a[7] += w.f * bfhi(v.w);
    }
  }
  // correctness tail for deg > 64 (statistically never taken here)
  for (int k = 64 + sg; k < dn; k += 4) {
    uint2 p = pairs[base + k];
    union { uint32_t u; float f; } w; w.u = p.y;
    uint4 v = reinterpret_cast<const uint4*>(xbf + (size_t)p.x * 64)[sl];
    a[0] += w.f * bflo(v.x); a[1] += w.f * bfhi(v.x);
    a[2] += w.f * bflo(v.y); a[3] += w.f * bfhi(v.y);
    a[4] += w.f * bflo(v.z); a[5] += w.f * bfhi(v.z);
    a[6] += w.f * bflo(v.w); a[7] += w.f * bfhi(v.w);
  }

  #pragma unroll
  for (int j = 0; j < 8; ++j) {
    a[j] += __shfl_xor(a[j], 16, 64);
    a[j] += __shfl_xor(a[j], 32, 64);
  }
  float ss = 0.f;
  #pragma unroll
  for (int j = 0; j < 8; ++j) ss += a[j] * a[j];
  ss += __shfl_xor(ss, 1, 64);
  ss += __shfl_xor(ss, 2, 64);
  ss += __shfl_xor(ss, 4, 64);
  ss += __shfl_xor(ss, 8, 64);
  float scale = 1.0f / fmaxf(sqrtf(ss), 1e-12f);
  if (lane < 16) {
    uint4 o;
    o.x = pack2bf(a[0] * scale, a[1] * scale);
    o.y = pack2bf(a[2] * scale, a[3] * scale);
    o.z = pack2bf(a[4] * scale, a[5] * scale);
    o.w = pack2bf(a[6] * scale, a[7] * scale);
    // ng cols 128+8*sl..+8 -> frag (t, ks=4+(sl>>2), lane=(sl&3)*16+rr)
    int t = n >> 4, rr = n & 15;
    reinterpret_cast<uint4*>(catf)[
        (size_t)(t * 8 + 4 + (sl >> 2)) * 64 + (sl & 3) * 16 + rr] = o;
  }
}

// ---------------- out = normalize(cat @ W^T + b), frag-major loads ----------
// One wave per 32-node tile (two 16-row subtiles sharing each B-frag load).
__global__ void __launch_bounds__(256) gemm_kernel(
    const uint32_t* __restrict__ catf, const uint32_t* __restrict__ wf,
    const float* __restrict__ bias, float* __restrict__ out, int N) {
  int wid = threadIdx.x >> 6;
  int lane = threadIdx.x & 63;
  int tile = blockIdx.x * 4 + wid;     // 32-row tile
  int node0 = tile * 32;
  if (node0 >= N) return;
  int r = lane & 15;
  int kg = lane >> 4;
  int t0 = tile * 2;                   // 16-row frag tiles t0, t0+1

  short8 a0[8], a1[8];
  #pragma unroll
  for (int ks = 0; ks < 8; ++ks) {
    a0[ks] = *reinterpret_cast<const short8*>(
        catf + ((size_t)(t0 * 8 + ks) * 64 + lane) * 4);
    a1[ks] = *reinterpret_cast<const short8*>(
        catf + ((size_t)((t0 + 1) * 8 + ks) * 64 + lane) * 4);
  }

  f32x4 acc0[8], acc1[8];
  #pragma unroll
  for (int nt = 0; nt < 8; ++nt) {
    acc0[nt] = (f32x4){0.f, 0.f, 0.f, 0.f};
    acc1[nt] = (f32x4){0.f, 0.f, 0.f, 0.f};
  }

  #pragma unroll
  for (int nt = 0; nt < 8; ++nt) {
    #pragma unroll
    for (int ks = 0; ks < 8; ++ks) {
      short8 bfrag = *reinterpret_cast<const short8*>(
          wf + ((size_t)(nt * 8 + ks) * 64 + lane) * 4);
      acc0[nt] = __builtin_amdgcn_mfma_f32_16x16x32_bf16(a0[ks], bfrag, acc0[nt], 0, 0, 0);
      acc1[nt] = __builtin_amdgcn_mfma_f32_16x16x32_bf16(a1[ks], bfrag, acc1[nt], 0, 0, 0);
    }
  }

  float bv[8];
  #pragma unroll
  for (int nt = 0; nt < 8; ++nt) bv[nt] = bias[nt * 16 + r];

  #pragma unroll
  for (int st = 0; st < 2; ++st) {
    f32x4* acc = st ? acc1 : acc0;
    int nodeb = node0 + st * 16;
    #pragma unroll
    for (int reg = 0; reg < 4; ++reg) {
      float ss = 0.f;
      #pragma unroll
      for (int nt = 0; nt < 8; ++nt) {
        float v = acc[nt][reg] + bv[nt];
        acc[nt][reg] = v;
        ss += v * v;
      }
      ss += __shfl_xor(ss, 1, 64);
      ss += __shfl_xor(ss, 2, 64);
      ss += __shfl_xor(ss, 4, 64);
      ss += __shfl_xor(ss, 8, 64);
      float scale = 1.0f / fmaxf(sqrtf(ss), 1e-12f);
      float* orow = out + (size_t)(nodeb + kg * 4 + reg) * 128;
      #pragma unroll
      for (int nt = 0; nt < 8; ++nt)
        orow[nt * 16 + r] = acc[nt][reg] * scale;
    }
  }
}

extern "C" void kernel_launch(void* const* d_in, const int* in_sizes, int n_in,
                              void* d_out, int out_size, void* d_ws, size_t ws_size,
                              hipStream_t stream) {
  const float* x    = (const float*)d_in[0];
  const int*   ei   = (const int*)d_in[1];   // [2, E]: row0 = src, row1 = dst
  const float* ew   = (const float*)d_in[2];
  const float* W    = (const float*)d_in[3];
  const float* bias = (const float*)d_in[4];
  float* out = (float*)d_out;

  int N = in_sizes[0] / 128;
  int E = in_sizes[1] / 2;
  const int* src = ei;
  const int* dst = ei + E;
  int nb = (N + 1023) / 1024;

  // d_ws: frag-major cat (N*128 u32), then frag-major W (16384 u32)
  uint32_t* catf = (uint32_t*)d_ws;
  uint32_t* wf   = catf + (size_t)N * 128;

  // d_out scratch (free until gemm overwrites d_out):
  // deg[N], partial[N], bsum[1024], boff[1024], pairs[E](uint2), pos[E],
  // xbf row-major bf16 x (N*64 u32)
  uint32_t* o       = (uint32_t*)d_out;
  uint32_t* deg     = o;
  uint32_t* partial = o + N;
  uint32_t* bsum    = o + 2 * (size_t)N;
  uint32_t* boff    = o + 2 * (size_t)N + 1024;
  uint2*    pairs   = (uint2*)(o + 2 * (size_t)N + 2048);
  uint32_t* pos     = o + 2 * (size_t)N + 2048 + 2 * (size_t)E;
  uint32_t* xbf     = o + 2 * (size_t)N + 2048 + 3 * (size_t)E;

  int eB = (E + 1023) / 1024;
  int xB = (N + 31) / 32;
  hipMemsetAsync(deg, 0, (size_t)N * sizeof(uint32_t), stream);
  prep_kernel<<<eB + xB + 16, 256, 0, stream>>>(
      dst, deg, pos, x, xbf, catf, W, wf, E, N, eB, xB);
  scan1_kernel<<<nb, 256, 0, stream>>>(deg, partial, bsum, N);
  scan2_kernel<<<1, 1024, 0, stream>>>(bsum, boff, nb);
  fill_kernel<<<(E + 255) / 256, 256, 0, stream>>>(src, dst, ew, partial, boff,
                                                   pos, pairs, E);
  gather_kernel<<<(N + 3) / 4, 256, 0, stream>>>(pairs, partial, boff, deg,
                                                 xbf, catf, N);
  int ntiles32 = (N + 31) / 32;
  gemm_kernel<<<(ntiles32 + 3) / 4, 256, 0, stream>>>(catf, wf, bias, out, N);
}

// Round 13
// 137.524 us; speedup vs baseline: 1.2131x; 1.0135x over previous
//
#include <hip/hip_runtime.h>
#include <stdint.h>

typedef __attribute__((ext_vector_type(8))) short short8;
typedef __attribute__((ext_vector_type(4))) float f32x4;

__device__ __forceinline__ uint32_t f2bf1(float f) {
  union { float f; uint32_t u; } c; c.f = f;
  return (c.u + 0x7FFFu + ((c.u >> 16) & 1u)) >> 16;
}
__device__ __forceinline__ uint32_t pack2bf(float lo, float hi) {
  return f2bf1(lo) | (f2bf1(hi) << 16);
}
__device__ __forceinline__ float bflo(uint32_t u) {
  union { uint32_t u; float f; } c; c.u = u << 16; return c.f;
}
__device__ __forceinline__ float bfhi(uint32_t u) {
  union { uint32_t u; float f; } c; c.u = u & 0xFFFF0000u; return c.f;
}

// Fragment layout: frag chunk (tile16 t, ks, lane) holds node t*16+(lane&15),
// cols ks*32 + (lane>>4)*8 .. +8 (one uint4). A wave's fragment load/store is
// one contiguous 1KB burst.

// ---- prep: [0,eB) count+pos x4 | [eB,eB+xB) x->xbf+catf via LDS transp | wf
__global__ void __launch_bounds__(256) prep_kernel(
    const int* __restrict__ dst, uint32_t* __restrict__ deg,
    uint32_t* __restrict__ pos,
    const float* __restrict__ x, uint32_t* __restrict__ xbf,
    uint32_t* __restrict__ catf,
    const float* __restrict__ W, uint32_t* __restrict__ wf,
    int E, int N, int eB, int xB) {
  __shared__ uint4 lds[16][17];   // padded: stride 17 uint4 kills conflicts
  int b = blockIdx.x;
  int ti = threadIdx.x;
  if (b < eB) {
    int e4 = (b * 256 + ti) * 4;
    if (e4 + 3 < E) {
      int4 d4 = *reinterpret_cast<const int4*>(dst + e4);
      uint4 p;
      p.x = atomicAdd(&deg[d4.x], 1u);
      p.y = atomicAdd(&deg[d4.y], 1u);
      p.z = atomicAdd(&deg[d4.z], 1u);
      p.w = atomicAdd(&deg[d4.w], 1u);
      *reinterpret_cast<uint4*>(pos + e4) = p;
    } else {
      for (int e = e4; e < E; ++e) pos[e] = atomicAdd(&deg[dst[e]], 1u);
    }
  } else if (b < eB + xB) {
    int tile = b - eB;
    int row = ti >> 4;            // node within tile (0..15)
    int cg  = ti & 15;            // col group of 8 (cols cg*8 .. cg*8+7)
    int n = tile * 16 + row;
    uint4 pk = make_uint4(0u, 0u, 0u, 0u);
    if (n < N) {
      const float* xp = x + (size_t)n * 128 + cg * 8;
      float4 f0 = reinterpret_cast<const float4*>(xp)[0];
      float4 f1 = reinterpret_cast<const float4*>(xp)[1];
      pk.x = pack2bf(f0.x, f0.y); pk.y = pack2bf(f0.z, f0.w);
      pk.z = pack2bf(f1.x, f1.y); pk.w = pack2bf(f1.z, f1.w);
      *reinterpret_cast<uint4*>(xbf + (size_t)n * 64 + cg * 4) = pk;
    }
    lds[row][cg] = pk;
    __syncthreads();
    // coalesced frag store: thread o -> chunk c=o>>6, lane l=o&63
    int c = ti >> 6, l = ti & 63;
    uint4 v = lds[l & 15][c * 4 + (l >> 4)];
    reinterpret_cast<uint4*>(catf)[(size_t)(tile * 8 + c) * 64 + l] = v;
  } else {
    int ch = (b - eB - xB) * 256 + ti;   // W frag chunk id
    if (ch < 4096) {
      int nt = ch >> 9, ks = (ch >> 6) & 7, lane = ch & 63;
      int rw = nt * 16 + (lane & 15);
      const float* wp = W + (size_t)rw * 256 + ks * 32 + (lane >> 4) * 8;
      float4 f0 = reinterpret_cast<const float4*>(wp)[0];
      float4 f1 = reinterpret_cast<const float4*>(wp)[1];
      uint4 pk;
      pk.x = pack2bf(f0.x, f0.y); pk.y = pack2bf(f0.z, f0.w);
      pk.z = pack2bf(f1.x, f1.y); pk.w = pack2bf(f1.z, f1.w);
      reinterpret_cast<uint4*>(wf)[ch] = pk;
    }
  }
}

// ---------------- scan stage 1: per-1024-chunk exclusive partials -----------
__global__ void __launch_bounds__(256) scan1_kernel(
    const uint32_t* __restrict__ deg, uint32_t* __restrict__ partial,
    uint32_t* __restrict__ bsum, int N) {
  __shared__ uint32_t sm[256];
  int t = threadIdx.x;
  int base = blockIdx.x * 1024 + t * 4;
  uint32_t d0 = 0, d1 = 0, d2 = 0, d3 = 0;
  if (base + 3 < N) {
    uint4 v = *reinterpret_cast<const uint4*>(deg + base);
    d0 = v.x; d1 = v.y; d2 = v.z; d3 = v.w;
  } else {
    if (base + 0 < N) d0 = deg[base + 0];
    if (base + 1 < N) d1 = deg[base + 1];
    if (base + 2 < N) d2 = deg[base + 2];
    if (base + 3 < N) d3 = deg[base + 3];
  }
  uint32_t s4 = d0 + d1 + d2 + d3;
  sm[t] = s4;
  uint32_t v = s4;
  __syncthreads();
  #pragma unroll
  for (int off = 1; off < 256; off <<= 1) {
    uint32_t u = (t >= off) ? sm[t - off] : 0u;
    __syncthreads();
    v += u;
    sm[t] = v;
    __syncthreads();
  }
  uint32_t ex = v - s4;
  if (base + 0 < N) partial[base + 0] = ex;
  if (base + 1 < N) partial[base + 1] = ex + d0;
  if (base + 2 < N) partial[base + 2] = ex + d0 + d1;
  if (base + 3 < N) partial[base + 3] = ex + d0 + d1 + d2;
  if (t == 255) bsum[blockIdx.x] = v;
}

// ---------------- scan stage 2: exclusive scan of block sums ----------------
__global__ void __launch_bounds__(1024) scan2_kernel(
    const uint32_t* __restrict__ bsum, uint32_t* __restrict__ boff, int nb) {
  __shared__ uint32_t sm[1024];
  int t = threadIdx.x;
  uint32_t s = (t < nb) ? bsum[t] : 0u;
  sm[t] = s;
  uint32_t v = s;
  __syncthreads();
  #pragma unroll
  for (int off = 1; off < 1024; off <<= 1) {
    uint32_t u = (t >= off) ? sm[t - off] : 0u;
    __syncthreads();
    v += u;
    sm[t] = v;
    __syncthreads();
  }
  if (t < nb) boff[t] = v - s;
}

// ---------------- CSR fill: no atomics (pos precomputed) --------------------
__global__ void __launch_bounds__(256) fill_kernel(
    const int* __restrict__ src, const int* __restrict__ dst,
    const float* __restrict__ ew, const uint32_t* __restrict__ partial,
    const uint32_t* __restrict__ boff, const uint32_t* __restrict__ pos,
    uint2* __restrict__ pairs, int E) {
  int e = blockIdx.x * 256 + threadIdx.x;
  if (e < E) {
    int d = dst[e];
    union { float f; uint32_t u; } w; w.f = ew[e];
    pairs[partial[d] + boff[d >> 10] + pos[e]] = make_uint2((uint32_t)src[e], w.u);
  }
}

// ------- Gather (row-major bf16 x reads) + normalize + frag-major write -----
__global__ void __launch_bounds__(256) gather_kernel(
    const uint2* __restrict__ pairs, const uint32_t* __restrict__ partial,
    const uint32_t* __restrict__ boff, const uint32_t* __restrict__ deg,
    const uint32_t* __restrict__ xbf, uint32_t* __restrict__ catf, int N) {
  int n = blockIdx.x * 4 + (threadIdx.x >> 6);
  if (n >= N) return;
  int lane = threadIdx.x & 63;
  int sg = lane >> 4;   // edge slot within iteration
  int sl = lane & 15;   // element slot: elems 8*sl .. 8*sl+7
  uint32_t base = partial[n] + boff[n >> 10];
  int dn = (int)deg[n];

  uint2 mp = (lane < dn) ? pairs[base + lane] : make_uint2(0u, 0u);

  float a[8] = {0.f, 0.f, 0.f, 0.f, 0.f, 0.f, 0.f, 0.f};
  int iters = (dn + 3) >> 2;
  for (int i = 0; i < iters; ++i) {
    int k = i * 4 + sg;
    uint32_t su = (uint32_t)__shfl((int)mp.x, k, 64);
    uint32_t wu = (uint32_t)__shfl((int)mp.y, k, 64);
    if (k < dn) {
      union { uint32_t u; float f; } w; w.u = wu;
      uint4 v = reinterpret_cast<const uint4*>(xbf + (size_t)su * 64)[sl];
      a[0] += w.f * bflo(v.x); a[1] += w.f * bfhi(v.x);
      a[2] += w.f * bflo(v.y); a[3] += w.f * bfhi(v.y);
      a[4] += w.f * bflo(v.z); a[5] += w.f * bfhi(v.z);
      a[6] += w.f * bflo(v.w); a[7] += w.f * bfhi(v.w);
    }
  }
  // correctness tail for deg > 64 (statistically never taken here)
  for (int k = 64 + sg; k < dn; k += 4) {
    uint2 p = pairs[base + k];
    union { uint32_t u; float f; } w; w.u = p.y;
    uint4 v = reinterpret_cast<const uint4*>(xbf + (size_t)p.x * 64)[sl];
    a[0] += w.f * bflo(v.x); a[1] += w.f * bfhi(v.x);
    a[2] += w.f * bflo(v.y); a[3] += w.f * bfhi(v.y);
    a[4] += w.f * bflo(v.z); a[5] += w.f * bfhi(v.z);
    a[6] += w.f * bflo(v.w); a[7] += w.f * bfhi(v.w);
  }

  #pragma unroll
  for (int j = 0; j < 8; ++j) {
    a[j] += __shfl_xor(a[j], 16, 64);
    a[j] += __shfl_xor(a[j], 32, 64);
  }
  float ss = 0.f;
  #pragma unroll
  for (int j = 0; j < 8; ++j) ss += a[j] * a[j];
  ss += __shfl_xor(ss, 1, 64);
  ss += __shfl_xor(ss, 2, 64);
  ss += __shfl_xor(ss, 4, 64);
  ss += __shfl_xor(ss, 8, 64);
  float scale = 1.0f / fmaxf(sqrtf(ss), 1e-12f);
  if (lane < 16) {
    uint4 o;
    o.x = pack2bf(a[0] * scale, a[1] * scale);
    o.y = pack2bf(a[2] * scale, a[3] * scale);
    o.z = pack2bf(a[4] * scale, a[5] * scale);
    o.w = pack2bf(a[6] * scale, a[7] * scale);
    // ng cols 128+8*sl..+8 -> frag (t, ks=4+(sl>>2), lane=(sl&3)*16+rr)
    int t = n >> 4, rr = n & 15;
    reinterpret_cast<uint4*>(catf)[
        (size_t)(t * 8 + 4 + (sl >> 2)) * 64 + (sl & 3) * 16 + rr] = o;
  }
}

// ---------------- out = normalize(cat @ W^T + b), frag-major loads ----------
// One wave per 32-node tile (two 16-row subtiles sharing each B-frag load).
__global__ void __launch_bounds__(256) gemm_kernel(
    const uint32_t* __restrict__ catf, const uint32_t* __restrict__ wf,
    const float* __restrict__ bias, float* __restrict__ out, int N) {
  int wid = threadIdx.x >> 6;
  int lane = threadIdx.x & 63;
  int tile = blockIdx.x * 4 + wid;     // 32-row tile
  int node0 = tile * 32;
  if (node0 >= N) return;
  int r = lane & 15;
  int kg = lane >> 4;
  int t0 = tile * 2;                   // 16-row frag tiles t0, t0+1

  short8 a0[8], a1[8];
  #pragma unroll
  for (int ks = 0; ks < 8; ++ks) {
    a0[ks] = *reinterpret_cast<const short8*>(
        catf + ((size_t)(t0 * 8 + ks) * 64 + lane) * 4);
    a1[ks] = *reinterpret_cast<const short8*>(
        catf + ((size_t)((t0 + 1) * 8 + ks) * 64 + lane) * 4);
  }

  f32x4 acc0[8], acc1[8];
  #pragma unroll
  for (int nt = 0; nt < 8; ++nt) {
    acc0[nt] = (f32x4){0.f, 0.f, 0.f, 0.f};
    acc1[nt] = (f32x4){0.f, 0.f, 0.f, 0.f};
  }

  #pragma unroll
  for (int nt = 0; nt < 8; ++nt) {
    #pragma unroll
    for (int ks = 0; ks < 8; ++ks) {
      short8 bfrag = *reinterpret_cast<const short8*>(
          wf + ((size_t)(nt * 8 + ks) * 64 + lane) * 4);
      acc0[nt] = __builtin_amdgcn_mfma_f32_16x16x32_bf16(a0[ks], bfrag, acc0[nt], 0, 0, 0);
      acc1[nt] = __builtin_amdgcn_mfma_f32_16x16x32_bf16(a1[ks], bfrag, acc1[nt], 0, 0, 0);
    }
  }

  float bv[8];
  #pragma unroll
  for (int nt = 0; nt < 8; ++nt) bv[nt] = bias[nt * 16 + r];

  #pragma unroll
  for (int st = 0; st < 2; ++st) {
    f32x4* acc = st ? acc1 : acc0;
    int nodeb = node0 + st * 16;
    #pragma unroll
    for (int reg = 0; reg < 4; ++reg) {
      float ss = 0.f;
      #pragma unroll
      for (int nt = 0; nt < 8; ++nt) {
        float v = acc[nt][reg] + bv[nt];
        acc[nt][reg] = v;
        ss += v * v;
      }
      ss += __shfl_xor(ss, 1, 64);
      ss += __shfl_xor(ss, 2, 64);
      ss += __shfl_xor(ss, 4, 64);
      ss += __shfl_xor(ss, 8, 64);
      float scale = 1.0f / fmaxf(sqrtf(ss), 1e-12f);
      float* orow = out + (size_t)(nodeb + kg * 4 + reg) * 128;
      #pragma unroll
      for (int nt = 0; nt < 8; ++nt)
        orow[nt * 16 + r] = acc[nt][reg] * scale;
    }
  }
}

extern "C" void kernel_launch(void* const* d_in, const int* in_sizes, int n_in,
                              void* d_out, int out_size, void* d_ws, size_t ws_size,
                              hipStream_t stream) {
  const float* x    = (const float*)d_in[0];
  const int*   ei   = (const int*)d_in[1];   // [2, E]: row0 = src, row1 = dst
  const float* ew   = (const float*)d_in[2];
  const float* W    = (const float*)d_in[3];
  const float* bias = (const float*)d_in[4];
  float* out = (float*)d_out;

  int N = in_sizes[0] / 128;
  int E = in_sizes[1] / 2;
  const int* src = ei;
  const int* dst = ei + E;
  int nb = (N + 1023) / 1024;

  // d_ws: frag-major cat (N*128 u32), then frag-major W (16384 u32)
  uint32_t* catf = (uint32_t*)d_ws;
  uint32_t* wf   = catf + (size_t)N * 128;

  // d_out scratch (free until gemm overwrites d_out):
  // deg[N], partial[N], bsum[1024], boff[1024], pairs[E](uint2), pos[E],
  // xbf row-major bf16 x (N*64 u32)
  uint32_t* o       = (uint32_t*)d_out;
  uint32_t* deg     = o;
  uint32_t* partial = o + N;
  uint32_t* bsum    = o + 2 * (size_t)N;
  uint32_t* boff    = o + 2 * (size_t)N + 1024;
  uint2*    pairs   = (uint2*)(o + 2 * (size_t)N + 2048);
  uint32_t* pos     = o + 2 * (size_t)N + 2048 + 2 * (size_t)E;
  uint32_t* xbf     = o + 2 * (size_t)N + 2048 + 3 * (size_t)E;

  int eB = (E + 1023) / 1024;
  int xB = (N + 15) / 16;
  hipMemsetAsync(deg, 0, (size_t)N * sizeof(uint32_t), stream);
  prep_kernel<<<eB + xB + 16, 256, 0, stream>>>(
      dst, deg, pos, x, xbf, catf, W, wf, E, N, eB, xB);
  scan1_kernel<<<nb, 256, 0, stream>>>(deg, partial, bsum, N);
  scan2_kernel<<<1, 1024, 0, stream>>>(bsum, boff, nb);
  fill_kernel<<<(E + 255) / 256, 256, 0, stream>>>(src, dst, ew, partial, boff,
                                                   pos, pairs, E);
  gather_kernel<<<(N + 3) / 4, 256, 0, stream>>>(pairs, partial, boff, deg,
                                                 xbf, catf, N);
  int ntiles32 = (N + 31) / 32;
  gemm_kernel<<<(ntiles32 + 3) / 4, 256, 0, stream>>>(catf, wf, bias, out, N);
}